// Round 4
// baseline (201.856 us; speedup 1.0000x reference)
//
#include <hip/hip_runtime.h>
#include <math.h>

#define CN 4096
#define KDIM 256
#define ND 256   // H * D
#define NH 4
#define DD 64
#define NEG 0.2f
#define L2E 1.44269504f

typedef __attribute__((ext_vector_type(8))) short short8;   // 8 bf16 (4 VGPRs)
typedef __attribute__((ext_vector_type(4))) float floatx4;  // MFMA acc

union S8I4 { int i[4]; short8 s; };

__device__ inline unsigned bfbits_rne(float f) {
  unsigned u = __float_as_uint(f);
  u += 0x7fffu + ((u >> 16) & 1u);
  return u >> 16;
}
__device__ inline float bf2f(unsigned hi) { return __uint_as_float(hi << 16); }

// pack two fp32 -> one dword of 2 bf16 (truncation) via v_perm
__device__ inline int pack2_trunc(float a, float b) {
  return (int)__builtin_amdgcn_perm(__float_as_uint(b), __float_as_uint(a), 0x07060302u);
}

// score (already log2e-scaled) -> exp2 with adjacency mask
__device__ inline float wval(float x, int a) {
  x = fmaxf(x, NEG * x);       // LeakyReLU (positive scale commutes)
  x = a ? x : -1e38f;          // mask -> exp2 -> 0
  return __builtin_amdgcn_exp2f(x);
}

// ---------------- Kernel 0: split W into bf16 hi/lo, transposed [c][k]
__global__ __launch_bounds__(256) void k_wcvt(const float* __restrict__ W,
                                              unsigned short* __restrict__ WT_hi,
                                              unsigned short* __restrict__ WT_lo) {
  const int t = threadIdx.x;
  const int c = blockIdx.x * 4 + (t >> 6);
  const int k0 = (t & 63) * 4;
  unsigned h[4], l[4];
#pragma unroll
  for (int j = 0; j < 4; ++j) {
    const float w = W[(size_t)(k0 + j) * ND + c];
    h[j] = bfbits_rne(w);
    l[j] = bfbits_rne(w - bf2f(h[j]));
  }
  uint2 vh, vl;
  vh.x = h[0] | (h[1] << 16); vh.y = h[2] | (h[3] << 16);
  vl.x = l[0] | (l[1] << 16); vl.y = l[2] | (l[3] << 16);
  *(uint2*)&WT_hi[(size_t)c * KDIM + k0] = vh;
  *(uint2*)&WT_lo[(size_t)c * KDIM + k0] = vl;
}

// ---------------- Kernel 1: h = x @ W via bf16 MFMA with hi/lo split (fp32-class)
// Grid (NH, CN/64), block 256 = 4 waves; wave = 16 rows x 64 cols (one head).
// No LDS, no barriers. Epilogue: hT bf16 [NH][DD][CN] + fused alpha (fp32).
__global__ __launch_bounds__(256) void k_gemm_h(const float* __restrict__ x,
                                                const unsigned short* __restrict__ WT_hi,
                                                const unsigned short* __restrict__ WT_lo,
                                                const float* __restrict__ a_src,
                                                const float* __restrict__ a_dst,
                                                unsigned short* __restrict__ hT,
                                                float* __restrict__ asrc,
                                                float* __restrict__ adst) {
  const int t = threadIdx.x;
  const int lane = t & 63, ww = t >> 6;
  const int n = lane & 15, q = lane >> 4;
  const int head = blockIdx.x;
  const int c0 = head * DD;
  const int i0 = blockIdx.y * 64 + ww * 16;
  const float* xr = x + (size_t)(i0 + n) * KDIM + q * 8;
  floatx4 acc[4] = {};
#pragma unroll 2
  for (int k0 = 0; k0 < KDIM; k0 += 32) {
    const float4 xa = *(const float4*)(xr + k0);
    const float4 xb = *(const float4*)(xr + k0 + 4);
    const float xs[8] = {xa.x, xa.y, xa.z, xa.w, xb.x, xb.y, xb.z, xb.w};
    S8I4 Ah, Al;
#pragma unroll
    for (int e = 0; e < 4; ++e) {
      const unsigned h0 = bfbits_rne(xs[2 * e]), h1 = bfbits_rne(xs[2 * e + 1]);
      const float r0 = xs[2 * e] - bf2f(h0), r1 = xs[2 * e + 1] - bf2f(h1);
      Ah.i[e] = (int)(h0 | (h1 << 16));
      Al.i[e] = (int)(bfbits_rne(r0) | (bfbits_rne(r1) << 16));
    }
#pragma unroll
    for (int tt = 0; tt < 4; ++tt) {
      const size_t boff = (size_t)(c0 + tt * 16 + n) * KDIM + k0 + q * 8;
      const short8 Bh = *(const short8*)(WT_hi + boff);
      const short8 Bl = *(const short8*)(WT_lo + boff);
      acc[tt] = __builtin_amdgcn_mfma_f32_16x16x32_bf16(Ah.s, Bh, acc[tt], 0, 0, 0);
      acc[tt] = __builtin_amdgcn_mfma_f32_16x16x32_bf16(Al.s, Bh, acc[tt], 0, 0, 0);
      acc[tt] = __builtin_amdgcn_mfma_f32_16x16x32_bf16(Ah.s, Bl, acc[tt], 0, 0, 0);
    }
  }
  // epilogue 1: hT[head][d = tt*16+n][i0 + q*4 + r] = bf16_rne(acc)
  unsigned short* hTb = hT + (size_t)head * DD * CN;
#pragma unroll
  for (int tt = 0; tt < 4; ++tt)
#pragma unroll
    for (int r = 0; r < 4; r += 2) {
      const unsigned d = bfbits_rne(acc[tt][r]) | (bfbits_rne(acc[tt][r + 1]) << 16);
      *(unsigned*)(hTb + (size_t)(tt * 16 + n) * CN + i0 + q * 4 + r) = d;
    }
  // epilogue 2: fused alpha from fp32 acc (C/D rows q*4+r, cols tt*16+n)
  float ps[4] = {}, pd[4] = {};
#pragma unroll
  for (int tt = 0; tt < 4; ++tt) {
    const float as = a_src[head * DD + tt * 16 + n];
    const float ad = a_dst[head * DD + tt * 16 + n];
#pragma unroll
    for (int r = 0; r < 4; ++r) {
      ps[r] += acc[tt][r] * as;
      pd[r] += acc[tt][r] * ad;
    }
  }
#pragma unroll
  for (int off = 1; off < 16; off <<= 1)
#pragma unroll
    for (int r = 0; r < 4; ++r) {
      ps[r] += __shfl_xor(ps[r], off);
      pd[r] += __shfl_xor(pd[r], off);
    }
  if (n == 0) {
#pragma unroll
    for (int r = 0; r < 4; ++r) {
      asrc[head * CN + i0 + q * 4 + r] = ps[r] * L2E;
      adst[head * CN + i0 + q * 4 + r] = pd[r] * L2E;
    }
  }
}

// ---------------- Kernel 2: fused masked softmax + attn@h, MFMA bf16
// Grid (NH, CN/16) = 1024 blocks; block 256 = 4 waves = 4 j-splits of the
// same 16 rows. Register double-buffered pipeline over K=32 subchunks.
__global__ __launch_bounds__(256, 4) void k_attn(const unsigned short* __restrict__ hT,
                                                 const int* __restrict__ adj,
                                                 const float* __restrict__ asrc,
                                                 const float* __restrict__ adst,
                                                 float* __restrict__ out) {
  __shared__ float red[3][20][64];  // [js-1][frag][lane], 15 KB
  const int t = threadIdx.x;
  const int lane = t & 63, js = t >> 6;
  const int n = lane & 15, q = lane >> 4;
  const int head = blockIdx.x;
  const int i0 = blockIdx.y * 16;
  const int i = i0 + n;  // A-frag row
  const float spre = asrc[head * CN + i];             // pre-scaled by log2(e)
  const int jb = js * 1024;
  const int* __restrict__ adjq = adj + (size_t)i * CN + q * 8;
  const float* __restrict__ adhq = adst + head * CN + q * 8;
  const unsigned short* __restrict__ hTq = hT + (size_t)head * DD * CN + q * 8;

  short8 ONES;
#pragma unroll
  for (int u = 0; u < 8; ++u) ONES[u] = (short)0x3F80;  // bf16 1.0

  floatx4 acc[4] = {};
  floatx4 accz = {};

  // double-buffered registers: B frags + adj + alpha_dst
  short8 B[2][4];
  int4 A0[2], A1[2];
  float4 D0[2], D1[2];

  auto LOAD = [&](int b, int j0) {
#pragma unroll
    for (int tt = 0; tt < 4; ++tt)
      B[b][tt] = *(const short8*)(hTq + (size_t)(tt * 16 + n) * CN + j0);
    A0[b] = *(const int4*)(adjq + j0);
    A1[b] = *(const int4*)(adjq + j0 + 4);
    D0[b] = *(const float4*)(adhq + j0);
    D1[b] = *(const float4*)(adhq + j0 + 4);
  };
  auto COMP = [&](int b) {
    float f[8];
    f[0] = wval(spre + D0[b].x, A0[b].x);
    f[1] = wval(spre + D0[b].y, A0[b].y);
    f[2] = wval(spre + D0[b].z, A0[b].z);
    f[3] = wval(spre + D0[b].w, A0[b].w);
    f[4] = wval(spre + D1[b].x, A1[b].x);
    f[5] = wval(spre + D1[b].y, A1[b].y);
    f[6] = wval(spre + D1[b].z, A1[b].z);
    f[7] = wval(spre + D1[b].w, A1[b].w);
    S8I4 A;
#pragma unroll
    for (int e = 0; e < 4; ++e) A.i[e] = pack2_trunc(f[2 * e], f[2 * e + 1]);
    accz = __builtin_amdgcn_mfma_f32_16x16x32_bf16(A.s, ONES, accz, 0, 0, 0);
#pragma unroll
    for (int tt = 0; tt < 4; ++tt)
      acc[tt] = __builtin_amdgcn_mfma_f32_16x16x32_bf16(A.s, B[b][tt], acc[tt], 0, 0, 0);
  };

  LOAD(0, jb);
  for (int sc = 0; sc < 32; sc += 2) {
    LOAD(1, jb + (sc + 1) * 32);
    COMP(0);
    LOAD(0, jb + (((sc + 2) & 31) * 32));  // last prefetch wraps (harmless re-read)
    COMP(1);
  }

  // combine 4 j-splits through LDS
  if (js > 0) {
#pragma unroll
    for (int tt = 0; tt < 4; ++tt)
#pragma unroll
      for (int r = 0; r < 4; ++r) red[js - 1][tt * 4 + r][lane] = acc[tt][r];
#pragma unroll
    for (int r = 0; r < 4; ++r) red[js - 1][16 + r][lane] = accz[r];
  }
  __syncthreads();
  if (js == 0) {
#pragma unroll
    for (int s = 0; s < 3; ++s) {
#pragma unroll
      for (int tt = 0; tt < 4; ++tt)
#pragma unroll
        for (int r = 0; r < 4; ++r) acc[tt][r] += red[s][tt * 4 + r][lane];
#pragma unroll
      for (int r = 0; r < 4; ++r) accz[r] += red[s][16 + r][lane];
    }
    // epilogue: C/D row = q*4+r, col = tt*16+n; divide by Z
#pragma unroll
    for (int r = 0; r < 4; ++r) {
      const float iz = 1.0f / accz[r];
      float* orow = out + (size_t)(i0 + q * 4 + r) * ND + head * DD + n;
#pragma unroll
      for (int tt = 0; tt < 4; ++tt) orow[tt * 16] = acc[tt][r] * iz;
    }
  }
}

extern "C" void kernel_launch(void* const* d_in, const int* in_sizes, int n_in,
                              void* d_out, int out_size, void* d_ws, size_t ws_size,
                              hipStream_t stream) {
  const float* x = (const float*)d_in[0];
  const int* adj = (const int*)d_in[1];
  const float* W = (const float*)d_in[2];
  const float* a_src = (const float*)d_in[3];
  const float* a_dst = (const float*)d_in[4];
  float* out = (float*)d_out;

  unsigned short* hT = (unsigned short*)d_ws;            // [NH][DD][CN] bf16 = 2 MB
  float* asrc = (float*)(hT + (size_t)NH * DD * CN);     // [NH][CN]
  float* adst = asrc + (size_t)NH * CN;                  // [NH][CN]
  unsigned short* WT_hi = (unsigned short*)(adst + (size_t)NH * CN);  // [ND][KDIM]
  unsigned short* WT_lo = WT_hi + (size_t)ND * KDIM;                  // [ND][KDIM]

  k_wcvt<<<dim3(ND / 4), 256, 0, stream>>>(W, WT_hi, WT_lo);
  k_gemm_h<<<dim3(NH, CN / 64), 256, 0, stream>>>(x, WT_hi, WT_lo, a_src, a_dst,
                                                  hT, asrc, adst);
  k_attn<<<dim3(NH, CN / 16), 256, 0, stream>>>(hT, adj, asrc, adst, out);
}

// Round 5
// 151.933 us; speedup vs baseline: 1.3286x; 1.3286x over previous
//
#include <hip/hip_runtime.h>
#include <math.h>

#define CN 4096
#define KDIM 256
#define ND 256   // H * D
#define NH 4
#define DD 64
#define NEG 0.2f
#define L2E 1.44269504f

typedef __attribute__((ext_vector_type(8))) short short8;   // 8 bf16 (4 VGPRs)
typedef __attribute__((ext_vector_type(4))) float floatx4;  // MFMA acc

union S8I4 { int i[4]; short8 s; };

__device__ inline unsigned bfbits_rne(float f) {
  unsigned u = __float_as_uint(f);
  u += 0x7fffu + ((u >> 16) & 1u);
  return u >> 16;
}
__device__ inline float bf2f(unsigned hi) { return __uint_as_float(hi << 16); }

// pack two fp32 -> one dword of 2 bf16 (truncation) via v_perm (verified R2-R4)
__device__ inline int pack2_trunc(float a, float b) {
  return (int)__builtin_amdgcn_perm(__float_as_uint(b), __float_as_uint(a), 0x07060302u);
}

// async global->LDS DMA: per-lane src, wave-uniform dst; lane L lands at dst + L*sz
#define GLDS(gp, lp, sz)                                                        \
  __builtin_amdgcn_global_load_lds(                                             \
      (const __attribute__((address_space(1))) void*)(gp),                      \
      (__attribute__((address_space(3))) void*)(lp), (sz), 0, 0)

// ---------------- Kernel 0: adj -> bitmask  +  W -> bf16 hi/lo transposed
__global__ __launch_bounds__(256) void k_prep(const int* __restrict__ adj,
                                              unsigned long long* __restrict__ mbits,
                                              const float* __restrict__ W,
                                              unsigned short* __restrict__ WT_hi,
                                              unsigned short* __restrict__ WT_lo) {
  const int bx = blockIdx.x;
  const int t = threadIdx.x;
  if (bx < 4096) {
    const int w = t >> 6, lane = t & 63;
    const size_t base = ((size_t)(bx * 4 + w)) * 1024;
#pragma unroll 4
    for (int it = 0; it < 16; ++it) {
      const size_t idx = base + (size_t)it * 64 + lane;
      const unsigned long long m = __ballot(adj[idx] != 0);
      if (lane == 0) mbits[idx >> 6] = m;
    }
  } else {
    const int c = (bx - 4096) * 4 + (t >> 6);
    const int k0 = (t & 63) * 4;
    unsigned h[4], l[4];
#pragma unroll
    for (int j = 0; j < 4; ++j) {
      const float w = W[(size_t)(k0 + j) * ND + c];
      h[j] = bfbits_rne(w);
      l[j] = bfbits_rne(w - bf2f(h[j]));
    }
    uint2 vh, vl;
    vh.x = h[0] | (h[1] << 16); vh.y = h[2] | (h[3] << 16);
    vl.x = l[0] | (l[1] << 16); vl.y = l[2] | (l[3] << 16);
    *(uint2*)&WT_hi[(size_t)c * KDIM + k0] = vh;
    *(uint2*)&WT_lo[(size_t)c * KDIM + k0] = vl;
  }
}

// ---------------- Kernel 1: h = x @ W via bf16 MFMA hi/lo split.
// Grid (NH, CN/64), 256 thr = 4 waves x 16 rows. W slice staged in LDS once.
__global__ __launch_bounds__(256, 2) void k_gemm_h(const float* __restrict__ x,
                                                   const unsigned short* __restrict__ WT_hi,
                                                   const unsigned short* __restrict__ WT_lo,
                                                   const float* __restrict__ a_src,
                                                   const float* __restrict__ a_dst,
                                                   unsigned short* __restrict__ hT,
                                                   float* __restrict__ asrc,
                                                   float* __restrict__ adst) {
  __shared__ __align__(16) unsigned short Whi_s[64 * 264];  // [c][k], pad 264
  __shared__ __align__(16) unsigned short Wlo_s[64 * 264];
  const int t = threadIdx.x;
  const int lane = t & 63, ww = t >> 6;
  const int n = lane & 15, q = lane >> 4;
  const int head = blockIdx.x;
  const int i0 = blockIdx.y * 64 + ww * 16;
  // stage whole per-head W hi/lo (32 KB each) into padded LDS
#pragma unroll
  for (int p = 0; p < 8; ++p) {
    const int s = p * 256 + t;
    const int c = s >> 5, kseg = s & 31;
    const size_t g = (size_t)(head * 64 + c) * KDIM + kseg * 8;
    *(short8*)&Whi_s[c * 264 + kseg * 8] = *(const short8*)(WT_hi + g);
    *(short8*)&Wlo_s[c * 264 + kseg * 8] = *(const short8*)(WT_lo + g);
  }
  const float* xr = x + (size_t)(i0 + n) * KDIM + q * 8;
  float4 xa = *(const float4*)(xr);
  float4 xb = *(const float4*)(xr + 4);
  __syncthreads();
  floatx4 acc[4] = {};
  for (int k0 = 0; k0 < KDIM; k0 += 32) {
    const float xs[8] = {xa.x, xa.y, xa.z, xa.w, xb.x, xb.y, xb.z, xb.w};
    if (k0 + 32 < KDIM) {  // prefetch next chunk
      xa = *(const float4*)(xr + k0 + 32);
      xb = *(const float4*)(xr + k0 + 36);
    }
    S8I4 Ah, Al;
#pragma unroll
    for (int e = 0; e < 4; ++e) {
      const unsigned h0 = bfbits_rne(xs[2 * e]), h1 = bfbits_rne(xs[2 * e + 1]);
      const float r0 = xs[2 * e] - bf2f(h0), r1 = xs[2 * e + 1] - bf2f(h1);
      Ah.i[e] = (int)(h0 | (h1 << 16));
      Al.i[e] = (int)(bfbits_rne(r0) | (bfbits_rne(r1) << 16));
    }
#pragma unroll
    for (int tt = 0; tt < 4; ++tt) {
      const int boff = (tt * 16 + n) * 264 + k0 + q * 8;
      const short8 Bh = *(const short8*)&Whi_s[boff];
      const short8 Bl = *(const short8*)&Wlo_s[boff];
      acc[tt] = __builtin_amdgcn_mfma_f32_16x16x32_bf16(Ah.s, Bh, acc[tt], 0, 0, 0);
      acc[tt] = __builtin_amdgcn_mfma_f32_16x16x32_bf16(Al.s, Bh, acc[tt], 0, 0, 0);
      acc[tt] = __builtin_amdgcn_mfma_f32_16x16x32_bf16(Ah.s, Bl, acc[tt], 0, 0, 0);
    }
  }
  // epilogue 1: hT[head][d = tt*16+n][i0 + q*4 + r] = bf16_rne(acc)  (verified R4)
  unsigned short* hTb = hT + (size_t)head * DD * CN;
#pragma unroll
  for (int tt = 0; tt < 4; ++tt)
#pragma unroll
    for (int r = 0; r < 4; r += 2) {
      const unsigned d = bfbits_rne(acc[tt][r]) | (bfbits_rne(acc[tt][r + 1]) << 16);
      *(unsigned*)(hTb + (size_t)(tt * 16 + n) * CN + i0 + q * 4 + r) = d;
    }
  // epilogue 2: fused alpha (pre-scaled by log2 e)  (verified R4)
  float ps[4] = {}, pd[4] = {};
#pragma unroll
  for (int tt = 0; tt < 4; ++tt) {
    const float as = a_src[head * DD + tt * 16 + n];
    const float ad = a_dst[head * DD + tt * 16 + n];
#pragma unroll
    for (int r = 0; r < 4; ++r) {
      ps[r] += acc[tt][r] * as;
      pd[r] += acc[tt][r] * ad;
    }
  }
#pragma unroll
  for (int off = 1; off < 16; off <<= 1)
#pragma unroll
    for (int r = 0; r < 4; ++r) {
      ps[r] += __shfl_xor(ps[r], off);
      pd[r] += __shfl_xor(pd[r], off);
    }
  if (n == 0) {
#pragma unroll
    for (int r = 0; r < 4; ++r) {
      asrc[head * CN + i0 + q * 4 + r] = ps[r] * L2E;
      adst[head * CN + i0 + q * 4 + r] = pd[r] * L2E;
    }
  }
}

// ---------------- Kernel 2: fused masked softmax + attn@h, async-DMA pipeline.
// Grid (CN/32, NH) = 512 blocks, 256 thr = 4 waves; wave ww = j-quarter of
// the block's 32 rows. Per-wave double-buffered LDS chunks (64 j), XOR-swizzled
// hT tiles, adjacency from bitmask, s_waitcnt vmcnt(10) keeps prefetch in flight.
__global__ __launch_bounds__(256, 2) void k_attn(const unsigned short* __restrict__ hT,
                                                 const unsigned* __restrict__ mbits32,
                                                 const float* __restrict__ asrc,
                                                 const float* __restrict__ adst,
                                                 float* __restrict__ out) {
  __shared__ __align__(16) char smem[4 * 2 * 8704];  // [wave][buf]{hT 8K|msk 256|ad 256}
  const int t = threadIdx.x;
  const int lane = t & 63, ww = t >> 6;
  const int n = lane & 15, q = lane >> 4;
  const int head = blockIdx.y;
  const int i0 = blockIdx.x * 32;
  const unsigned short* __restrict__ hTb = hT + (size_t)head * DD * CN;
  const float* __restrict__ adh = adst + head * CN;
  const int jbase = ww * 1024;  // this wave's j-quarter

  float sp0 = asrc[head * CN + i0 + n];
  float sp1 = asrc[head * CN + i0 + 16 + n];
  asm volatile("" : "+v"(sp0), "+v"(sp1));  // materialize before DMA stream starts

  // per-lane invariant DMA source offsets
  const int dl = lane >> 3, jbl = (lane & 7) ^ (lane >> 3);
  const unsigned hoff = (unsigned)dl * CN + jbl * 8;            // elements
  const unsigned moff = (unsigned)(i0 + (lane >> 1)) * 128 + (lane & 1);  // dwords
  char* const wbase = smem + ww * 2 * 8704;

  short8 ONES;
#pragma unroll
  for (int u = 0; u < 8; ++u) ONES[u] = (short)0x3F80;  // bf16 1.0

  floatx4 acc[2][4] = {};
  floatx4 accz[2] = {};

  auto ISSUE = [&](int b, int j0) {
    char* base = wbase + b * 8704;
#pragma unroll
    for (int w8 = 0; w8 < 8; ++w8)
      GLDS(hTb + (size_t)(w8 * 8) * CN + hoff + j0, base + w8 * 1024, 16);
    GLDS(mbits32 + moff + (j0 >> 5), base + 8192, 4);
    GLDS(adh + j0 + lane, base + 8448, 4);
  };

  ISSUE(0, jbase);
  for (int c = 0; c < 16; ++c) {
    const int b = c & 1;
    const int jn = jbase + ((c + 1) & 15) * 64;  // last iter re-reads chunk 0 (harmless)
    ISSUE(b ^ 1, jn);
    // wait for chunk c's 10 DMAs, keep chunk c+1's 10 in flight
    asm volatile("s_waitcnt vmcnt(10)" ::: "memory");
    const char* base = wbase + b * 8704;
    short8 B[4][2];
#pragma unroll
    for (int tt = 0; tt < 4; ++tt)
#pragma unroll
      for (int f = 0; f < 2; ++f)
        B[tt][f] = *(const short8*)(base + (tt * 16 + n) * 128 +
                                    ((((f << 2) | q) ^ (n & 7)) << 4));
    const uint2 mk0 = *(const uint2*)(base + 8192 + n * 8);
    const uint2 mk1 = *(const uint2*)(base + 8192 + (16 + n) * 8);
    const float* adl = (const float*)(base + 8448);
#pragma unroll
    for (int f = 0; f < 2; ++f) {
      const float4 a0 = *(const float4*)(adl + f * 32 + q * 8);
      const float4 a1 = *(const float4*)(adl + f * 32 + q * 8 + 4);
      const float ade[8] = {a0.x, a0.y, a0.z, a0.w, a1.x, a1.y, a1.z, a1.w};
#pragma unroll
      for (int rg = 0; rg < 2; ++rg) {
        const unsigned mw = f ? (rg ? mk1.y : mk0.y) : (rg ? mk1.x : mk0.x);
        const unsigned mbyte = (mw >> (q * 8)) & 255u;
        const float sp = rg ? sp1 : sp0;
        float fv[8];
#pragma unroll
        for (int e = 0; e < 8; ++e) {
          float xv = sp + ade[e];
          xv = fmaxf(xv, NEG * xv);
          xv = ((mbyte >> e) & 1u) ? xv : -1e38f;
          fv[e] = __builtin_amdgcn_exp2f(xv);
        }
        S8I4 A;
#pragma unroll
        for (int e = 0; e < 4; ++e) A.i[e] = pack2_trunc(fv[2 * e], fv[2 * e + 1]);
        accz[rg] = __builtin_amdgcn_mfma_f32_16x16x32_bf16(A.s, ONES, accz[rg], 0, 0, 0);
#pragma unroll
        for (int tt = 0; tt < 4; ++tt)
          acc[rg][tt] =
              __builtin_amdgcn_mfma_f32_16x16x32_bf16(A.s, B[tt][f], acc[rg][tt], 0, 0, 0);
      }
    }
  }

  // combine the 4 j-quarter waves through LDS (staging regions reused)
  __syncthreads();
  float* red = (float*)smem;  // [3][2][20][64]
  if (ww > 0) {
#pragma unroll
    for (int rg = 0; rg < 2; ++rg) {
      float* rb = red + ((ww - 1) * 2 + rg) * 1280;
#pragma unroll
      for (int tt = 0; tt < 4; ++tt)
#pragma unroll
        for (int r = 0; r < 4; ++r) rb[(tt * 4 + r) * 64 + lane] = acc[rg][tt][r];
#pragma unroll
      for (int r = 0; r < 4; ++r) rb[(16 + r) * 64 + lane] = accz[rg][r];
    }
  }
  __syncthreads();
  if (ww == 0) {
#pragma unroll
    for (int s = 0; s < 3; ++s)
#pragma unroll
      for (int rg = 0; rg < 2; ++rg) {
        const float* rb = red + (s * 2 + rg) * 1280;
#pragma unroll
        for (int tt = 0; tt < 4; ++tt)
#pragma unroll
          for (int r = 0; r < 4; ++r) acc[rg][tt][r] += rb[(tt * 4 + r) * 64 + lane];
#pragma unroll
        for (int r = 0; r < 4; ++r) accz[rg][r] += rb[(16 + r) * 64 + lane];
      }
#pragma unroll
    for (int rg = 0; rg < 2; ++rg)
#pragma unroll
      for (int r = 0; r < 4; ++r) {
        const float iz = 1.0f / accz[rg][r];
        float* orow = out + (size_t)(i0 + rg * 16 + q * 4 + r) * ND + head * DD + n;
#pragma unroll
        for (int tt = 0; tt < 4; ++tt) orow[tt * 16] = acc[rg][tt][r] * iz;
      }
  }
}

extern "C" void kernel_launch(void* const* d_in, const int* in_sizes, int n_in,
                              void* d_out, int out_size, void* d_ws, size_t ws_size,
                              hipStream_t stream) {
  const float* x = (const float*)d_in[0];
  const int* adj = (const int*)d_in[1];
  const float* W = (const float*)d_in[2];
  const float* a_src = (const float*)d_in[3];
  const float* a_dst = (const float*)d_in[4];
  float* out = (float*)d_out;

  unsigned short* hT = (unsigned short*)d_ws;                         // 2 MB
  float* asrc = (float*)(hT + (size_t)NH * DD * CN);                  // 64 KB
  float* adst = asrc + (size_t)NH * CN;                               // 64 KB
  unsigned short* WT_hi = (unsigned short*)(adst + (size_t)NH * CN);  // 128 KB
  unsigned short* WT_lo = WT_hi + (size_t)ND * KDIM;                  // 128 KB
  unsigned long long* mbits = (unsigned long long*)(WT_lo + (size_t)ND * KDIM);  // 2 MB

  k_prep<<<dim3(4096 + ND / 4), 256, 0, stream>>>(adj, mbits, W, WT_hi, WT_lo);
  k_gemm_h<<<dim3(NH, CN / 64), 256, 0, stream>>>(x, WT_hi, WT_lo, a_src, a_dst,
                                                  hT, asrc, adst);
  k_attn<<<dim3(CN / 32, NH), 256, 0, stream>>>(hT, (const unsigned*)mbits,
                                                asrc, adst, out);
}